// Round 20
// baseline (250.361 us; speedup 1.0000x reference)
//
#include <hip/hip_runtime.h>
#include <stdint.h>

// Problem constants
#define BB 4
#define TT 1024
#define DIM 2048
#define NH 16
#define HD 128
#define MR 4096   // BB*TT rows
#define QKVS (3 * DIM)   // 6144: row stride of fused qkv buffer

typedef __attribute__((ext_vector_type(4))) float    f32x4;
typedef __attribute__((ext_vector_type(8))) uint16_t u16x8;
typedef __attribute__((ext_vector_type(4))) uint16_t u16x4;
typedef __attribute__((ext_vector_type(4))) short    s16x4;
typedef __attribute__((ext_vector_type(8))) __bf16   bf16x8;

static __device__ __forceinline__ uint16_t f2bf(float f) {
  uint32_t u = __builtin_bit_cast(uint32_t, f);
  u += 0x7fffu + ((u >> 16) & 1u);   // round-to-nearest-even
  return (uint16_t)(u >> 16);
}
static __device__ __forceinline__ float bf2f(uint16_t b) {
  uint32_t u = ((uint32_t)b) << 16;
  return __builtin_bit_cast(float, u);
}

static __device__ __forceinline__ f32x4 mfma16(u16x8 a, u16x8 b, f32x4 c) {
  return __builtin_amdgcn_mfma_f32_16x16x32_bf16(
      __builtin_bit_cast(bf16x8, a), __builtin_bit_cast(bf16x8, b), c, 0, 0, 0);
}

// async global->LDS, 16B per lane; LDS dest = wave-uniform base + lane*16
static __device__ __forceinline__ void load_lds_16B(const void* g, void* l) {
  __builtin_amdgcn_global_load_lds(
      (const __attribute__((address_space(1))) void*)g,
      (__attribute__((address_space(3))) void*)l, 16, 0, 0);
}

// hardware transpose read, NO embedded wait (batched by caller; see tr_fence).
#if defined(__has_builtin) && __has_builtin(__builtin_amdgcn_ds_read_tr16_b64_v4i16)
#define TR_BUILTIN 1
#else
#define TR_BUILTIN 0
#endif
static __device__ __forceinline__ u16x4 tr16_nw(const uint16_t* base, int byteoff) {
  __attribute__((address_space(3))) char* ap =
      (__attribute__((address_space(3))) char*)(void*)base + byteoff;
#if TR_BUILTIN
  s16x4 r = __builtin_amdgcn_ds_read_tr16_b64_v4i16(
      (__attribute__((address_space(3))) s16x4*)ap);
  return __builtin_bit_cast(u16x4, r);
#else
  u16x4 d;
  uint32_t a32 = (uint32_t)(uintptr_t)ap;
  asm volatile("ds_read_b64_tr_b16 %0, %1" : "=&v"(d) : "v"(a32));
  return d;
#endif
}
static __device__ __forceinline__ void tr_fence() {
#if !TR_BUILTIN
  asm volatile("s_waitcnt lgkmcnt(0)" ::: "memory");
  __builtin_amdgcn_sched_barrier(0);
#endif
}

// ---------------- fused cast: x + wq|wk|wv|wo in ONE launch ------------------
__global__ __launch_bounds__(256) void cast_all(const float* __restrict__ x,
                                                const float* __restrict__ wq,
                                                const float* __restrict__ wk,
                                                const float* __restrict__ wv,
                                                const float* __restrict__ wo,
                                                uint16_t* __restrict__ xb,
                                                uint16_t* __restrict__ wall) {
  const int xn = 8388608 / 4;    // f32x4 chunks in x
  const int wn = 4194304 / 4;    // per weight matrix
  int i = blockIdx.x * 256 + threadIdx.x;   // [0, xn + 4*wn)
  const float* src;
  uint16_t* dst;
  int j, dj;
  if (i < xn) {
    src = x; dst = xb; j = i; dj = i;
  } else {
    const int k   = i - xn;
    const int sel = k / wn;
    j  = k - sel * wn;
    dj = k;                       // wall = wqkv|wob contiguous
    src = (sel == 0) ? wq : (sel == 1) ? wk : (sel == 2) ? wv : wo;
    dst = wall;
  }
  f32x4 v = ((const f32x4*)src)[j];
  u16x4 o;
  o[0] = f2bf(v[0]); o[1] = f2bf(v[1]); o[2] = f2bf(v[2]); o[3] = f2bf(v[3]);
  ((u16x4*)dst)[dj] = o;
}

// ---------------- GEMM 128x128, BK=64, m97 + supertile + nt-stores -----------
// r10 core + r19 L2-aware 4x4 supertile ordering (FETCH 283->117 MB, 43.5%
// MfmaUtil). NEW (r20): non-temporal C-stores on streaming outputs (MODE 2
// qkv, MODE 1 f32 out) so the 50+33 MB write streams don't evict B-panels
// from L2/L3 between supercolumn passes (targets remaining 117->40 MB fetch).
// MODE: 0 = bf16 out (cached), 1 = f32 out (nt), 2 = bf16 + fused RoPE (nt),
//       with 1/sqrt(HD) folded into the q half (cols [0, DIM)).
template <int MODE>
__global__ __launch_bounds__(256) void gemm_m97(const uint16_t* __restrict__ A,
                                                const uint16_t* __restrict__ Bt,
                                                float* __restrict__ Cf,
                                                uint16_t* __restrict__ Cb,
                                                const float* __restrict__ cosT,
                                                const float* __restrict__ sinT,
                                                int M, int N, int K) {
  __shared__ __attribute__((aligned(16))) uint16_t As[128][64];
  __shared__ __attribute__((aligned(16))) uint16_t Bs[128][64];
  const int tid  = threadIdx.x;
  const int lane = tid & 63;
  const int wave = tid >> 6;
  const int lrow = lane & 15;
  const int lgrp = lane >> 4;
  const int wr   = (wave >> 1) * 64;
  const int wc   = (wave & 1) * 64;

  // XCD band + 4x4 supertile ordering (requires nby==32, nbx%4==0)
  const int xcd = (int)blockIdx.x & 7;
  const int c   = (int)blockIdx.x >> 3;   // [0, nwg/8) position within band
  const int wi  = c & 15;                 // position within 4x4 supertile
  const int st  = c >> 4;                 // supertile (supercolumn) index
  const long bRow = (long)(xcd * 4 + (wi & 3)) << 7;
  const long bCol = (long)(st * 4 + (wi >> 2)) << 7;

  const f32x4 fz = {0.f, 0.f, 0.f, 0.f};
  f32x4 acc[4][4];
#pragma unroll
  for (int m = 0; m < 4; ++m)
#pragma unroll
    for (int n = 0; n < 4; ++n) acc[m][n] = fz;

  const int nkt = K >> 6;
  for (int kt = 0; kt < nkt; ++kt) {
    const long kb = (long)kt << 6;
    __syncthreads();   // all waves done reading the previous tile
#pragma unroll
    for (int i = 0; i < 4; ++i) {
      const int L   = (i * 256 + tid) * 16;       // linear LDS byte position
      const int row = L >> 7;                     // 0..127 (128 B per row)
      const int gc  = (((L >> 4) & 7) ^ (row & 7)) * 8;   // pre-swizzled col
      load_lds_16B(A  + (bRow + row) * (long)K + kb + gc, (char*)&As[0][0] + L);
      load_lds_16B(Bt + (bCol + row) * (long)K + kb + gc, (char*)&Bs[0][0] + L);
    }
    __syncthreads();   // staged data visible (compiler drains vmcnt here)

#pragma unroll
    for (int kk = 0; kk < 2; ++kk) {
      u16x8 af[4], bf[4];
#pragma unroll
      for (int m = 0; m < 4; ++m) {
        const int row = wr + m * 16 + lrow;
        const int ch  = (kk * 4 + lgrp) ^ (row & 7);
        af[m] = *(const u16x8*)((const char*)&As[0][0] + row * 128 + ch * 16);
      }
#pragma unroll
      for (int n = 0; n < 4; ++n) {
        const int row = wc + n * 16 + lrow;
        const int ch  = (kk * 4 + lgrp) ^ (row & 7);
        bf[n] = *(const u16x8*)((const char*)&Bs[0][0] + row * 128 + ch * 16);
      }
      __builtin_amdgcn_s_setprio(1);
#pragma unroll
      for (int m = 0; m < 4; ++m)
#pragma unroll
        for (int n = 0; n < 4; ++n) acc[m][n] = mfma16(af[m], bf[n], acc[m][n]);
      __builtin_amdgcn_s_setprio(0);
    }
  }

  // epilogue (MODE 2: fused RoPE on q/k column range, scale folded into q)
  const bool doRope = (MODE == 2) && (bCol < 2 * DIM);
  const bool isQ    = (MODE == 2) && (bCol < DIM);   // block-uniform (128-wide)
  const float qscale = isQ ? 0.08838834764831845f : 1.0f;  // 1/sqrt(128)
#pragma unroll
  for (int m = 0; m < 4; ++m)
#pragma unroll
    for (int n = 0; n < 4; ++n) {
      const long grow0 = bRow + wr + m * 16 + lgrp * 4;
      const long gcol  = bCol + wc + n * 16 + lrow;
      if (doRope) {
        const int  fi  = ((int)gcol >> 1) & 63;
        const bool odd = (gcol & 1) != 0;
#pragma unroll
        for (int r = 0; r < 4; ++r) {
          const long grow = grow0 + r;
          const int  ttt  = (int)grow & (TT - 1);
          float v = acc[m][n][r];
          float p = __shfl_xor(v, 1, 64);   // partner column (lane^1)
          float cc = cosT[ttt * 64 + fi];
          float ss = sinT[ttt * 64 + fi];
          float o  = odd ? (p * ss + v * cc) : (v * cc - p * ss);
          __builtin_nontemporal_store(f2bf(o * qscale),
                                      &Cb[grow * (long)N + gcol]);
        }
      } else {
#pragma unroll
        for (int r = 0; r < 4; ++r) {
          const long idx = (grow0 + r) * (long)N + gcol;
          if (MODE == 1) __builtin_nontemporal_store(acc[m][n][r], &Cf[idx]);
          else if (MODE == 2) __builtin_nontemporal_store(f2bf(acc[m][n][r]),
                                                          &Cb[idx]);
          else Cb[idx] = f2bf(acc[m][n][r]);
        }
      }
    }
}

// ---------------- Flash attention fwd (8 waves share K/V staging) ------------
// r18-proven: grid (BB*NH, TT/128), 512 thr = 8 waves, each wave 16 q-rows;
// one 64-kv K/V tile staged per barrier pair, consumed by all 8 waves.
// Lazy softmax, packed PsT, batched tr-reads. UNCHANGED.
__global__ __launch_bounds__(512) void attn_fwd(const uint16_t* __restrict__ Q,
                                                const uint16_t* __restrict__ K,
                                                const uint16_t* __restrict__ V,
                                                uint16_t* __restrict__ O) {
  __shared__ __attribute__((aligned(16))) uint16_t Ks[64 * 128];    // 16 KB
  __shared__ __attribute__((aligned(16))) uint16_t Vs[64 * 128];    // 16 KB
  __shared__ __attribute__((aligned(16))) uint16_t PsT[8][64 * 16]; // 16 KB
  const int tid  = threadIdx.x;
  const int lane = tid & 63;
  const int wave = tid >> 6;          // 0..7
  const int lrow = lane & 15;
  const int lgrp = lane >> 4;
  const int b  = blockIdx.x >> 4;
  const int h  = blockIdx.x & 15;
  const int qt = blockIdx.y;
  const long colBase = (long)h * HD;
  const long rs = QKVS;
  const long os = DIM;
  const long qrow0 = (long)b * TT + qt * 128 + wave * 16;

  u16x8 qf[4];
#pragma unroll
  for (int kkk = 0; kkk < 4; ++kkk)
    qf[kkk] = *(const u16x8*)(Q + (qrow0 + lrow) * rs + colBase + kkk * 32 + lgrp * 8);

  const f32x4 fz = {0.f, 0.f, 0.f, 0.f};
  f32x4 oacc[8];
#pragma unroll
  for (int nf = 0; nf < 8; ++nf) oacc[nf] = fz;
  float mst[4] = {-1e30f, -1e30f, -1e30f, -1e30f};
  float lst[4] = {0.f, 0.f, 0.f, 0.f};   // per-lane partial sums

  for (int kt2 = 0; kt2 < TT / 64; ++kt2) {
    const long krow = (long)b * TT + kt2 * 64;
    __syncthreads();   // all waves done reading the previous tile
    // stage 64-kv K + V with 512 threads: 2 issues each (16B/lane)
#pragma unroll
    for (int i = 0; i < 2; ++i) {
      const int L = (i * 512 + tid) * 16;
      const int krw = L >> 8;
      const int ksc = ((L >> 4) & 15) ^ (krw & 7);
      load_lds_16B(K + (krow + krw) * rs + colBase + ksc * 8, (char*)Ks + L);
      const int vbl = L >> 11;
      const int vkv = ((L >> 7) & 15) * 4 + ((L >> 5) & 3);
      const int vd  = vbl * 16 + ((L >> 4) & 1) * 8;
      load_lds_16B(V + (krow + vkv) * rs + colBase + vd, (char*)Vs + L);
    }
    __syncthreads();   // staged data visible (compiler drains vmcnt here)

    // S = Q K^T (Q pre-scaled): 16x64 per wave
    f32x4 sacc[4];
#pragma unroll
    for (int n = 0; n < 4; ++n) sacc[n] = fz;
    __builtin_amdgcn_s_setprio(1);
#pragma unroll
    for (int kkk = 0; kkk < 4; ++kkk) {
#pragma unroll
      for (int n = 0; n < 4; ++n) {
        const int row = n * 16 + lrow;
        const int ch  = (kkk * 4 + lgrp) ^ (row & 7);
        u16x8 bfr = *(const u16x8*)((const char*)Ks + row * 256 + ch * 16);
        sacc[n] = mfma16(qf[kkk], bfr, sacc[n]);
      }
    }
    __builtin_amdgcn_s_setprio(0);

    // lazy defer-max: per-lane max only; no butterfly in the common path
    float pm[4];
#pragma unroll
    for (int r = 0; r < 4; ++r)
      pm[r] = fmaxf(fmaxf(sacc[0][r], sacc[1][r]), fmaxf(sacc[2][r], sacc[3][r]));
    bool need = false;
#pragma unroll
    for (int r = 0; r < 4; ++r) need = need || (pm[r] > mst[r] + 8.0f);
    if (__any(need)) {   // rare after tile 0
      float rmax[4];
#pragma unroll
      for (int r = 0; r < 4; ++r) rmax[r] = pm[r];
#pragma unroll
      for (int off = 8; off >= 1; off >>= 1)
#pragma unroll
        for (int r = 0; r < 4; ++r)
          rmax[r] = fmaxf(rmax[r], __shfl_xor(rmax[r], off, 64));
#pragma unroll
      for (int r = 0; r < 4; ++r) {
        float mnew  = fmaxf(mst[r], rmax[r]);
        float alpha = __expf(mst[r] - mnew);   // row-uniform
        mst[r] = mnew;
        lst[r] *= alpha;                        // per-lane partial: linear scale
#pragma unroll
        for (int nf = 0; nf < 8; ++nf) oacc[nf][r] *= alpha;
      }
    }

    // P = exp(S - m): pack 4 consecutive-q bf16 into ONE b64 write (PsT).
    const int cb = (lgrp ^ (lrow >> 2)) * 4;
#pragma unroll
    for (int n = 0; n < 4; ++n) {
      float e0 = __expf(sacc[n][0] - mst[0]);
      float e1 = __expf(sacc[n][1] - mst[1]);
      float e2 = __expf(sacc[n][2] - mst[2]);
      float e3 = __expf(sacc[n][3] - mst[3]);
      lst[0] += e0; lst[1] += e1; lst[2] += e2; lst[3] += e3;
      u16x4 pk;
      pk[0] = f2bf(e0); pk[1] = f2bf(e1); pk[2] = f2bf(e2); pk[3] = f2bf(e3);
      *(u16x4*)&PsT[wave][(n * 16 + lrow) * 16 + cb] = pk;
    }

    // PsT write->read is same-wave cross-lane: wait for LDS writes to land.
    asm volatile("s_waitcnt lgkmcnt(0)" ::: "memory");

    // O += P V : A-frag via 2 tr-reads on PsT, V via 16 tr-reads, one fence.
    __builtin_amdgcn_s_setprio(1);
#pragma unroll
    for (int kk2 = 0; kk2 < 2; ++kk2) {
      const int t0 = kk2 * 8 + lgrp * 2;
      u16x4 alo = tr16_nw(&PsT[wave][0],
                          t0 * 128 + ((lrow ^ (t0 & 3)) << 3));
      u16x4 ahi = tr16_nw(&PsT[wave][0],
                          (t0 + 1) * 128 + ((lrow ^ ((t0 + 1) & 3)) << 3));
      u16x4 vlo[8], vhi[8];
#pragma unroll
      for (int nf = 0; nf < 8; ++nf) {
        const int vbase = nf * 2048 + kk2 * 1024 + lgrp * 256 + lrow * 8;
        vlo[nf] = tr16_nw(Vs, vbase);
        vhi[nf] = tr16_nw(Vs, vbase + 128);
      }
      tr_fence();
      u16x8 af;
      af[0] = alo[0]; af[1] = alo[1]; af[2] = alo[2]; af[3] = alo[3];
      af[4] = ahi[0]; af[5] = ahi[1]; af[6] = ahi[2]; af[7] = ahi[3];
#pragma unroll
      for (int nf = 0; nf < 8; ++nf) {
        u16x8 bfr;
        bfr[0] = vlo[nf][0]; bfr[1] = vlo[nf][1];
        bfr[2] = vlo[nf][2]; bfr[3] = vlo[nf][3];
        bfr[4] = vhi[nf][0]; bfr[5] = vhi[nf][1];
        bfr[6] = vhi[nf][2]; bfr[7] = vhi[nf][3];
        oacc[nf] = mfma16(af, bfr, oacc[nf]);
      }
    }
    __builtin_amdgcn_s_setprio(0);
  }

  // single end-of-block reduction of the per-lane l partials (row = 16 lanes)
#pragma unroll
  for (int off = 8; off >= 1; off >>= 1)
#pragma unroll
    for (int r = 0; r < 4; ++r) lst[r] += __shfl_xor(lst[r], off, 64);

  float inv[4];
#pragma unroll
  for (int r = 0; r < 4; ++r) inv[r] = 1.0f / lst[r];
#pragma unroll
  for (int nf = 0; nf < 8; ++nf)
#pragma unroll
    for (int r = 0; r < 4; ++r)
      O[(qrow0 + lgrp * 4 + r) * os + colBase + nf * 16 + lrow] =
          f2bf(oacc[nf][r] * inv[r]);
}

// ---------------- launch ----------------------------------------------------
extern "C" void kernel_launch(void* const* d_in, const int* in_sizes, int n_in,
                              void* d_out, int out_size, void* d_ws, size_t ws_size,
                              hipStream_t stream) {
  const float* x  = (const float*)d_in[0];
  const float* fc = (const float*)d_in[1];
  const float* fs = (const float*)d_in[2];
  const float* wq = (const float*)d_in[3];
  const float* wk = (const float*)d_in[4];
  const float* wv = (const float*)d_in[5];
  const float* wo = (const float*)d_in[6];
  float* out = (float*)d_out;

  uint16_t* w16  = (uint16_t*)d_ws;
  uint16_t* xb   = w16;                   //  8,388,608  x  [4096][2048]
  uint16_t* wqkv = xb + 8388608;          // 12,582,912  [6144][2048]
  uint16_t* wob  = wqkv + 12582912;       //  4,194,304  [2048][2048] (contig after wqkv)
  uint16_t* qkv  = wob + 4194304;         // 25,165,824  [4096][6144]
  uint16_t* ob   = qkv + 25165824;        //  8,388,608  [4096][2048]

  // one fused cast launch: x -> xb, wq|wk|wv|wo -> wqkv..wob (contiguous)
  cast_all<<<(8388608 / 4 + 4 * (4194304 / 4)) / 256, 256, 0, stream>>>(
      x, wq, wk, wv, wo, xb, wqkv);

  // fused QKV projection + RoPE epilogue (q pre-scaled by 1/sqrt(HD))
  gemm_m97<2><<<(MR / 128) * (QKVS / 128), 256, 0, stream>>>(
      xb, wqkv, nullptr, qkv, fc, fs, MR, QKVS, DIM);

  // attention: Q,K,V strided views into qkv; 8 waves / 128 q-rows per block
  dim3 ga(BB * NH, TT / 128);
  attn_fwd<<<ga, 512, 0, stream>>>(qkv, qkv + DIM, qkv + 2 * DIM, ob);

  // output projection -> fp32 d_out
  gemm_m97<1><<<(MR / 128) * (DIM / 128), 256, 0, stream>>>(
      ob, wob, out, nullptr, nullptr, nullptr, MR, DIM, DIM);
}

// Round 21
// 224.678 us; speedup vs baseline: 1.1143x; 1.1143x over previous
//
#include <hip/hip_runtime.h>
#include <stdint.h>

// Problem constants
#define BB 4
#define TT 1024
#define DIM 2048
#define NH 16
#define HD 128
#define MR 4096   // BB*TT rows
#define QKVS (3 * DIM)   // 6144: row stride of fused qkv buffer

typedef __attribute__((ext_vector_type(4))) float    f32x4;
typedef __attribute__((ext_vector_type(8))) uint16_t u16x8;
typedef __attribute__((ext_vector_type(4))) uint16_t u16x4;
typedef __attribute__((ext_vector_type(4))) short    s16x4;
typedef __attribute__((ext_vector_type(8))) __bf16   bf16x8;

static __device__ __forceinline__ uint16_t f2bf(float f) {
  uint32_t u = __builtin_bit_cast(uint32_t, f);
  u += 0x7fffu + ((u >> 16) & 1u);   // round-to-nearest-even
  return (uint16_t)(u >> 16);
}
static __device__ __forceinline__ float bf2f(uint16_t b) {
  uint32_t u = ((uint32_t)b) << 16;
  return __builtin_bit_cast(float, u);
}

static __device__ __forceinline__ f32x4 mfma16(u16x8 a, u16x8 b, f32x4 c) {
  return __builtin_amdgcn_mfma_f32_16x16x32_bf16(
      __builtin_bit_cast(bf16x8, a), __builtin_bit_cast(bf16x8, b), c, 0, 0, 0);
}

// async global->LDS, 16B per lane; LDS dest = wave-uniform base + lane*16
static __device__ __forceinline__ void load_lds_16B(const void* g, void* l) {
  __builtin_amdgcn_global_load_lds(
      (const __attribute__((address_space(1))) void*)g,
      (__attribute__((address_space(3))) void*)l, 16, 0, 0);
}

// hardware transpose read, NO embedded wait (batched by caller; see tr_fence).
#if defined(__has_builtin) && __has_builtin(__builtin_amdgcn_ds_read_tr16_b64_v4i16)
#define TR_BUILTIN 1
#else
#define TR_BUILTIN 0
#endif
static __device__ __forceinline__ u16x4 tr16_nw(const uint16_t* base, int byteoff) {
  __attribute__((address_space(3))) char* ap =
      (__attribute__((address_space(3))) char*)(void*)base + byteoff;
#if TR_BUILTIN
  s16x4 r = __builtin_amdgcn_ds_read_tr16_b64_v4i16(
      (__attribute__((address_space(3))) s16x4*)ap);
  return __builtin_bit_cast(u16x4, r);
#else
  u16x4 d;
  uint32_t a32 = (uint32_t)(uintptr_t)ap;
  asm volatile("ds_read_b64_tr_b16 %0, %1" : "=&v"(d) : "v"(a32));
  return d;
#endif
}
static __device__ __forceinline__ void tr_fence() {
#if !TR_BUILTIN
  asm volatile("s_waitcnt lgkmcnt(0)" ::: "memory");
  __builtin_amdgcn_sched_barrier(0);
#endif
}

// ---------------- fused cast: x + wq|wk|wv|wo in ONE launch ------------------
__global__ __launch_bounds__(256) void cast_all(const float* __restrict__ x,
                                                const float* __restrict__ wq,
                                                const float* __restrict__ wk,
                                                const float* __restrict__ wv,
                                                const float* __restrict__ wo,
                                                uint16_t* __restrict__ xb,
                                                uint16_t* __restrict__ wall) {
  const int xn = 8388608 / 4;    // f32x4 chunks in x
  const int wn = 4194304 / 4;    // per weight matrix
  int i = blockIdx.x * 256 + threadIdx.x;   // [0, xn + 4*wn)
  const float* src;
  uint16_t* dst;
  int j, dj;
  if (i < xn) {
    src = x; dst = xb; j = i; dj = i;
  } else {
    const int k   = i - xn;
    const int sel = k / wn;
    j  = k - sel * wn;
    dj = k;                       // wall = wqkv|wob contiguous
    src = (sel == 0) ? wq : (sel == 1) ? wk : (sel == 2) ? wv : wo;
    dst = wall;
  }
  f32x4 v = ((const f32x4*)src)[j];
  u16x4 o;
  o[0] = f2bf(v[0]); o[1] = f2bf(v[1]); o[2] = f2bf(v[2]); o[3] = f2bf(v[3]);
  ((u16x4*)dst)[dj] = o;
}

// ---------------- GEMM 128x128, BK=64, m97 + supertile (r19-proven) ----------
// r10 core + r19 L2-aware 4x4 supertile ordering: each XCD owns a 4-row band
// (nby==32 = 8 XCDs x 4 rows); within the band, blocks iterate 4x4 supertiles
// (4 A-rows 2MB + 4 B-cols 2MB = one XCD's 4MB L2). FETCH 283->117 MB,
// QKV 937 TF, MfmaUtil 43.5%, MfmaUtil+VALUBusy ~86% (issue-saturated).
// r20's nt-stores REVERTED: scalar 2B nt stores bypass L2 write-combining
// (WRITE_SIZE 49->90 MB, dur +30 us) — refuted, normal stores restored.
// MODE: 0 = bf16 out, 1 = f32 out, 2 = bf16 out + fused RoPE on cols [0,2*DIM)
//       with 1/sqrt(HD) folded into the q half (cols [0, DIM)).
template <int MODE>
__global__ __launch_bounds__(256) void gemm_m97(const uint16_t* __restrict__ A,
                                                const uint16_t* __restrict__ Bt,
                                                float* __restrict__ Cf,
                                                uint16_t* __restrict__ Cb,
                                                const float* __restrict__ cosT,
                                                const float* __restrict__ sinT,
                                                int M, int N, int K) {
  __shared__ __attribute__((aligned(16))) uint16_t As[128][64];
  __shared__ __attribute__((aligned(16))) uint16_t Bs[128][64];
  const int tid  = threadIdx.x;
  const int lane = tid & 63;
  const int wave = tid >> 6;
  const int lrow = lane & 15;
  const int lgrp = lane >> 4;
  const int wr   = (wave >> 1) * 64;
  const int wc   = (wave & 1) * 64;

  // XCD band + 4x4 supertile ordering (requires nby==32, nbx%4==0)
  const int xcd = (int)blockIdx.x & 7;
  const int c   = (int)blockIdx.x >> 3;   // [0, nwg/8) position within band
  const int wi  = c & 15;                 // position within 4x4 supertile
  const int st  = c >> 4;                 // supertile (supercolumn) index
  const long bRow = (long)(xcd * 4 + (wi & 3)) << 7;
  const long bCol = (long)(st * 4 + (wi >> 2)) << 7;

  const f32x4 fz = {0.f, 0.f, 0.f, 0.f};
  f32x4 acc[4][4];
#pragma unroll
  for (int m = 0; m < 4; ++m)
#pragma unroll
    for (int n = 0; n < 4; ++n) acc[m][n] = fz;

  const int nkt = K >> 6;
  for (int kt = 0; kt < nkt; ++kt) {
    const long kb = (long)kt << 6;
    __syncthreads();   // all waves done reading the previous tile
#pragma unroll
    for (int i = 0; i < 4; ++i) {
      const int L   = (i * 256 + tid) * 16;       // linear LDS byte position
      const int row = L >> 7;                     // 0..127 (128 B per row)
      const int gc  = (((L >> 4) & 7) ^ (row & 7)) * 8;   // pre-swizzled col
      load_lds_16B(A  + (bRow + row) * (long)K + kb + gc, (char*)&As[0][0] + L);
      load_lds_16B(Bt + (bCol + row) * (long)K + kb + gc, (char*)&Bs[0][0] + L);
    }
    __syncthreads();   // staged data visible (compiler drains vmcnt here)

#pragma unroll
    for (int kk = 0; kk < 2; ++kk) {
      u16x8 af[4], bf[4];
#pragma unroll
      for (int m = 0; m < 4; ++m) {
        const int row = wr + m * 16 + lrow;
        const int ch  = (kk * 4 + lgrp) ^ (row & 7);
        af[m] = *(const u16x8*)((const char*)&As[0][0] + row * 128 + ch * 16);
      }
#pragma unroll
      for (int n = 0; n < 4; ++n) {
        const int row = wc + n * 16 + lrow;
        const int ch  = (kk * 4 + lgrp) ^ (row & 7);
        bf[n] = *(const u16x8*)((const char*)&Bs[0][0] + row * 128 + ch * 16);
      }
      __builtin_amdgcn_s_setprio(1);
#pragma unroll
      for (int m = 0; m < 4; ++m)
#pragma unroll
        for (int n = 0; n < 4; ++n) acc[m][n] = mfma16(af[m], bf[n], acc[m][n]);
      __builtin_amdgcn_s_setprio(0);
    }
  }

  // epilogue (MODE 2: fused RoPE on q/k column range, scale folded into q)
  const bool doRope = (MODE == 2) && (bCol < 2 * DIM);
  const bool isQ    = (MODE == 2) && (bCol < DIM);   // block-uniform (128-wide)
  const float qscale = isQ ? 0.08838834764831845f : 1.0f;  // 1/sqrt(128)
#pragma unroll
  for (int m = 0; m < 4; ++m)
#pragma unroll
    for (int n = 0; n < 4; ++n) {
      const long grow0 = bRow + wr + m * 16 + lgrp * 4;
      const long gcol  = bCol + wc + n * 16 + lrow;
      if (doRope) {
        const int  fi  = ((int)gcol >> 1) & 63;
        const bool odd = (gcol & 1) != 0;
#pragma unroll
        for (int r = 0; r < 4; ++r) {
          const long grow = grow0 + r;
          const int  ttt  = (int)grow & (TT - 1);
          float v = acc[m][n][r];
          float p = __shfl_xor(v, 1, 64);   // partner column (lane^1)
          float cc = cosT[ttt * 64 + fi];
          float ss = sinT[ttt * 64 + fi];
          float o  = odd ? (p * ss + v * cc) : (v * cc - p * ss);
          Cb[grow * (long)N + gcol] = f2bf(o * qscale);
        }
      } else {
#pragma unroll
        for (int r = 0; r < 4; ++r) {
          const long idx = (grow0 + r) * (long)N + gcol;
          if (MODE == 1) Cf[idx] = acc[m][n][r];
          else           Cb[idx] = f2bf(acc[m][n][r]);
        }
      }
    }
}

// ---------------- Flash attention fwd (8 waves share K/V staging) ------------
// r18-proven: grid (BB*NH, TT/128), 512 thr = 8 waves, each wave 16 q-rows;
// one 64-kv K/V tile staged per barrier pair, consumed by all 8 waves.
// Lazy softmax, packed PsT, batched tr-reads. UNCHANGED.
__global__ __launch_bounds__(512) void attn_fwd(const uint16_t* __restrict__ Q,
                                                const uint16_t* __restrict__ K,
                                                const uint16_t* __restrict__ V,
                                                uint16_t* __restrict__ O) {
  __shared__ __attribute__((aligned(16))) uint16_t Ks[64 * 128];    // 16 KB
  __shared__ __attribute__((aligned(16))) uint16_t Vs[64 * 128];    // 16 KB
  __shared__ __attribute__((aligned(16))) uint16_t PsT[8][64 * 16]; // 16 KB
  const int tid  = threadIdx.x;
  const int lane = tid & 63;
  const int wave = tid >> 6;          // 0..7
  const int lrow = lane & 15;
  const int lgrp = lane >> 4;
  const int b  = blockIdx.x >> 4;
  const int h  = blockIdx.x & 15;
  const int qt = blockIdx.y;
  const long colBase = (long)h * HD;
  const long rs = QKVS;
  const long os = DIM;
  const long qrow0 = (long)b * TT + qt * 128 + wave * 16;

  u16x8 qf[4];
#pragma unroll
  for (int kkk = 0; kkk < 4; ++kkk)
    qf[kkk] = *(const u16x8*)(Q + (qrow0 + lrow) * rs + colBase + kkk * 32 + lgrp * 8);

  const f32x4 fz = {0.f, 0.f, 0.f, 0.f};
  f32x4 oacc[8];
#pragma unroll
  for (int nf = 0; nf < 8; ++nf) oacc[nf] = fz;
  float mst[4] = {-1e30f, -1e30f, -1e30f, -1e30f};
  float lst[4] = {0.f, 0.f, 0.f, 0.f};   // per-lane partial sums

  for (int kt2 = 0; kt2 < TT / 64; ++kt2) {
    const long krow = (long)b * TT + kt2 * 64;
    __syncthreads();   // all waves done reading the previous tile
    // stage 64-kv K + V with 512 threads: 2 issues each (16B/lane)
#pragma unroll
    for (int i = 0; i < 2; ++i) {
      const int L = (i * 512 + tid) * 16;
      const int krw = L >> 8;
      const int ksc = ((L >> 4) & 15) ^ (krw & 7);
      load_lds_16B(K + (krow + krw) * rs + colBase + ksc * 8, (char*)Ks + L);
      const int vbl = L >> 11;
      const int vkv = ((L >> 7) & 15) * 4 + ((L >> 5) & 3);
      const int vd  = vbl * 16 + ((L >> 4) & 1) * 8;
      load_lds_16B(V + (krow + vkv) * rs + colBase + vd, (char*)Vs + L);
    }
    __syncthreads();   // staged data visible (compiler drains vmcnt here)

    // S = Q K^T (Q pre-scaled): 16x64 per wave
    f32x4 sacc[4];
#pragma unroll
    for (int n = 0; n < 4; ++n) sacc[n] = fz;
    __builtin_amdgcn_s_setprio(1);
#pragma unroll
    for (int kkk = 0; kkk < 4; ++kkk) {
#pragma unroll
      for (int n = 0; n < 4; ++n) {
        const int row = n * 16 + lrow;
        const int ch  = (kkk * 4 + lgrp) ^ (row & 7);
        u16x8 bfr = *(const u16x8*)((const char*)Ks + row * 256 + ch * 16);
        sacc[n] = mfma16(qf[kkk], bfr, sacc[n]);
      }
    }
    __builtin_amdgcn_s_setprio(0);

    // lazy defer-max: per-lane max only; no butterfly in the common path
    float pm[4];
#pragma unroll
    for (int r = 0; r < 4; ++r)
      pm[r] = fmaxf(fmaxf(sacc[0][r], sacc[1][r]), fmaxf(sacc[2][r], sacc[3][r]));
    bool need = false;
#pragma unroll
    for (int r = 0; r < 4; ++r) need = need || (pm[r] > mst[r] + 8.0f);
    if (__any(need)) {   // rare after tile 0
      float rmax[4];
#pragma unroll
      for (int r = 0; r < 4; ++r) rmax[r] = pm[r];
#pragma unroll
      for (int off = 8; off >= 1; off >>= 1)
#pragma unroll
        for (int r = 0; r < 4; ++r)
          rmax[r] = fmaxf(rmax[r], __shfl_xor(rmax[r], off, 64));
#pragma unroll
      for (int r = 0; r < 4; ++r) {
        float mnew  = fmaxf(mst[r], rmax[r]);
        float alpha = __expf(mst[r] - mnew);   // row-uniform
        mst[r] = mnew;
        lst[r] *= alpha;                        // per-lane partial: linear scale
#pragma unroll
        for (int nf = 0; nf < 8; ++nf) oacc[nf][r] *= alpha;
      }
    }

    // P = exp(S - m): pack 4 consecutive-q bf16 into ONE b64 write (PsT).
    const int cb = (lgrp ^ (lrow >> 2)) * 4;
#pragma unroll
    for (int n = 0; n < 4; ++n) {
      float e0 = __expf(sacc[n][0] - mst[0]);
      float e1 = __expf(sacc[n][1] - mst[1]);
      float e2 = __expf(sacc[n][2] - mst[2]);
      float e3 = __expf(sacc[n][3] - mst[3]);
      lst[0] += e0; lst[1] += e1; lst[2] += e2; lst[3] += e3;
      u16x4 pk;
      pk[0] = f2bf(e0); pk[1] = f2bf(e1); pk[2] = f2bf(e2); pk[3] = f2bf(e3);
      *(u16x4*)&PsT[wave][(n * 16 + lrow) * 16 + cb] = pk;
    }

    // PsT write->read is same-wave cross-lane: wait for LDS writes to land.
    asm volatile("s_waitcnt lgkmcnt(0)" ::: "memory");

    // O += P V : A-frag via 2 tr-reads on PsT, V via 16 tr-reads, one fence.
    __builtin_amdgcn_s_setprio(1);
#pragma unroll
    for (int kk2 = 0; kk2 < 2; ++kk2) {
      const int t0 = kk2 * 8 + lgrp * 2;
      u16x4 alo = tr16_nw(&PsT[wave][0],
                          t0 * 128 + ((lrow ^ (t0 & 3)) << 3));
      u16x4 ahi = tr16_nw(&PsT[wave][0],
                          (t0 + 1) * 128 + ((lrow ^ ((t0 + 1) & 3)) << 3));
      u16x4 vlo[8], vhi[8];
#pragma unroll
      for (int nf = 0; nf < 8; ++nf) {
        const int vbase = nf * 2048 + kk2 * 1024 + lgrp * 256 + lrow * 8;
        vlo[nf] = tr16_nw(Vs, vbase);
        vhi[nf] = tr16_nw(Vs, vbase + 128);
      }
      tr_fence();
      u16x8 af;
      af[0] = alo[0]; af[1] = alo[1]; af[2] = alo[2]; af[3] = alo[3];
      af[4] = ahi[0]; af[5] = ahi[1]; af[6] = ahi[2]; af[7] = ahi[3];
#pragma unroll
      for (int nf = 0; nf < 8; ++nf) {
        u16x8 bfr;
        bfr[0] = vlo[nf][0]; bfr[1] = vlo[nf][1];
        bfr[2] = vlo[nf][2]; bfr[3] = vlo[nf][3];
        bfr[4] = vhi[nf][0]; bfr[5] = vhi[nf][1];
        bfr[6] = vhi[nf][2]; bfr[7] = vhi[nf][3];
        oacc[nf] = mfma16(af, bfr, oacc[nf]);
      }
    }
    __builtin_amdgcn_s_setprio(0);
  }

  // single end-of-block reduction of the per-lane l partials (row = 16 lanes)
#pragma unroll
  for (int off = 8; off >= 1; off >>= 1)
#pragma unroll
    for (int r = 0; r < 4; ++r) lst[r] += __shfl_xor(lst[r], off, 64);

  float inv[4];
#pragma unroll
  for (int r = 0; r < 4; ++r) inv[r] = 1.0f / lst[r];
#pragma unroll
  for (int nf = 0; nf < 8; ++nf)
#pragma unroll
    for (int r = 0; r < 4; ++r)
      O[(qrow0 + lgrp * 4 + r) * os + colBase + nf * 16 + lrow] =
          f2bf(oacc[nf][r] * inv[r]);
}

// ---------------- launch ----------------------------------------------------
extern "C" void kernel_launch(void* const* d_in, const int* in_sizes, int n_in,
                              void* d_out, int out_size, void* d_ws, size_t ws_size,
                              hipStream_t stream) {
  const float* x  = (const float*)d_in[0];
  const float* fc = (const float*)d_in[1];
  const float* fs = (const float*)d_in[2];
  const float* wq = (const float*)d_in[3];
  const float* wk = (const float*)d_in[4];
  const float* wv = (const float*)d_in[5];
  const float* wo = (const float*)d_in[6];
  float* out = (float*)d_out;

  uint16_t* w16  = (uint16_t*)d_ws;
  uint16_t* xb   = w16;                   //  8,388,608  x  [4096][2048]
  uint16_t* wqkv = xb + 8388608;          // 12,582,912  [6144][2048]
  uint16_t* wob  = wqkv + 12582912;       //  4,194,304  [2048][2048] (contig after wqkv)
  uint16_t* qkv  = wob + 4194304;         // 25,165,824  [4096][6144]
  uint16_t* ob   = qkv + 25165824;        //  8,388,608  [4096][2048]

  // one fused cast launch: x -> xb, wq|wk|wv|wo -> wqkv..wob (contiguous)
  cast_all<<<(8388608 / 4 + 4 * (4194304 / 4)) / 256, 256, 0, stream>>>(
      x, wq, wk, wv, wo, xb, wqkv);

  // fused QKV projection + RoPE epilogue (q pre-scaled by 1/sqrt(HD))
  gemm_m97<2><<<(MR / 128) * (QKVS / 128), 256, 0, stream>>>(
      xb, wqkv, nullptr, qkv, fc, fs, MR, QKVS, DIM);

  // attention: Q,K,V strided views into qkv; 8 waves / 128 q-rows per block
  dim3 ga(BB * NH, TT / 128);
  attn_fwd<<<ga, 512, 0, stream>>>(qkv, qkv + DIM, qkv + 2 * DIM, ob);

  // output projection -> fp32 d_out
  gemm_m97<1><<<(MR / 128) * (DIM / 128), 256, 0, stream>>>(
      ob, wob, out, nullptr, nullptr, nullptr, MR, DIM, DIM);
}